// Round 1
// baseline (224.391 us; speedup 1.0000x reference)
//
#include <hip/hip_runtime.h>
#include <hip/hip_bf16.h>

#define C_DIM 384
#define H_NUM 6
#define HS    64
#define B_DIM 128
#define T_DIM 256
#define NROWS (B_DIM * T_DIM)  // 32768

typedef unsigned short u16;
typedef unsigned int u32;
typedef short bf16x8 __attribute__((ext_vector_type(8)));
typedef float floatx4 __attribute__((ext_vector_type(4)));

__device__ __forceinline__ u16 f2b(float f) {
  __hip_bfloat16 h = __float2bfloat16(f);
  u16 u;
  __builtin_memcpy(&u, &h, 2);
  return u;
}
// async global->LDS, 16B per lane. LDS dest is wave-uniform base + lane*16.
__device__ __forceinline__ void gload_lds16(const void* g, void* lds) {
  __builtin_amdgcn_global_load_lds(
      (const __attribute__((address_space(1))) u32*)g,
      (__attribute__((address_space(3))) u32*)lds, 16, 0, 0);
}

// ---------------------------------------------------------------------------
// Prep (merged): x fp32 -> bf16 xb  AND  weights -> bf16.
// Wh  [h][192][384]: rows = [Wq_h^T(64); Wk_h^T(64); Wv_h^T(64)].
// Wpt [n=384][c=384].
// Grid: 6144 blocks for x (8 elems/thread), 2304 blocks for weights.
// ---------------------------------------------------------------------------
__global__ __launch_bounds__(256) void prep_kernel(
    const float* __restrict__ x, const float* __restrict__ Wq,
    const float* __restrict__ Wk, const float* __restrict__ Wv,
    const float* __restrict__ Wp, u16* __restrict__ xb,
    u16* __restrict__ Wh, u16* __restrict__ Wpt) {
  const int bid = blockIdx.x;
  const int tid = threadIdx.x;
  if (bid < 6144) {  // x: 12,582,912 elems = 6144*256 chunks of 8
    const int i = bid * 256 + tid;
    const float4 f0 = ((const float4*)x)[i * 2];
    const float4 f1 = ((const float4*)x)[i * 2 + 1];
    bf16x8 pk;
    pk[0] = (short)f2b(f0.x); pk[1] = (short)f2b(f0.y);
    pk[2] = (short)f2b(f0.z); pk[3] = (short)f2b(f0.w);
    pk[4] = (short)f2b(f1.x); pk[5] = (short)f2b(f1.y);
    pk[6] = (short)f2b(f1.z); pk[7] = (short)f2b(f1.w);
    ((bf16x8*)xb)[i] = pk;
  } else {  // weights: 442368 + 147456 = 589824 = 2304*256
    const int idx = (bid - 6144) * 256 + tid;
    const int WHN = H_NUM * 192 * C_DIM;  // 442368
    if (idx < WHN) {
      int h = idx / (192 * C_DIM);
      int rem = idx % (192 * C_DIM);
      int r = rem / C_DIM, c = rem % C_DIM;
      int tz = r >> 6, d = r & 63;
      const float* W = (tz == 0) ? Wq : (tz == 1) ? Wk : Wv;
      Wh[idx] = f2b(W[((size_t)h * C_DIM + c) * HS + d]);
    } else {
      int j = idx - WHN;
      int n = j / C_DIM, c = j % C_DIM;
      Wpt[j] = f2b(Wp[c * C_DIM + n]);
    }
  }
}

// ---------------------------------------------------------------------------
// Kernel A: QKV projection. Block = 128 rows x ONE HEAD (N=192: q|k|v cols).
// 4 waves, wave tile 64x96 (acc 4x6). BK=64, async bf16 staging (m97-style).
// q,k -> [bh][t][d]; v -> LDS transpose -> vT [bh][d][t].
// LDS: As 16K + Bs 24K = 40960 B; Ts[64][136] aliases As.
// ---------------------------------------------------------------------------
__global__ __launch_bounds__(256) void qkv_gemm(
    const u16* __restrict__ xb, const u16* __restrict__ Wh,
    u16* __restrict__ q, u16* __restrict__ k, u16* __restrict__ vT) {
  __shared__ u16 smem[20480];  // 40960 B
  u16* As = smem;           // [128][64]
  u16* Bs = smem + 8192;    // [192][64]
  u16* Ts = smem;           // [64][136] v-transpose, aliases As (+Bs head)
  const int row0 = blockIdx.x * 128;
  const int h = blockIdx.y;
  const u16* a_rows = xb + (size_t)row0 * C_DIM;
  const u16* wbase = Wh + (size_t)h * 192 * C_DIM;

  const int tid = threadIdx.x;
  const int lane = tid & 63;
  const int w = tid >> 6;
  const int lr = lane >> 3;        // staging row within 8-row strip
  const int lkc = (lane & 7) * 8;  // staging col
  const int qd = lane >> 4;
  const int ln = lane & 15;
  const int wm = (w & 1) * 64;     // m-offset (64-row half)
  const int wn = (w >> 1) * 96;    // n-offset (96-col half)

  floatx4 acc[4][6];
#pragma unroll
  for (int i = 0; i < 4; ++i)
#pragma unroll
    for (int j = 0; j < 6; ++j) acc[i][j] = floatx4{0.f, 0.f, 0.f, 0.f};

  for (int kb = 0; kb < C_DIM / 64; ++kb) {
    const int k0 = kb * 64;
    __syncthreads();
    // A: 16 strips of 8 rows / 4 waves = 4 per wave
#pragma unroll
    for (int s = 0; s < 4; ++s) {
      const int rbase = (s * 4 + w) * 8;
      gload_lds16(a_rows + (size_t)(rbase + lr) * C_DIM + k0 + lkc,
                  As + rbase * 64);
    }
    // B: 24 strips of 8 rows / 4 waves = 6 per wave
#pragma unroll
    for (int s = 0; s < 6; ++s) {
      const int rbase = (s * 4 + w) * 8;
      gload_lds16(wbase + (size_t)(rbase + lr) * C_DIM + k0 + lkc,
                  Bs + rbase * 64);
    }
    __syncthreads();

#pragma unroll
    for (int kk = 0; kk < 2; ++kk) {
      bf16x8 af[4], bf[6];
#pragma unroll
      for (int mt = 0; mt < 4; ++mt)
        af[mt] = *(const bf16x8*)&As[(wm + mt * 16 + ln) * 64 + kk * 32 + qd * 8];
#pragma unroll
      for (int nt = 0; nt < 6; ++nt)
        bf[nt] = *(const bf16x8*)&Bs[(wn + nt * 16 + ln) * 64 + kk * 32 + qd * 8];
#pragma unroll
      for (int mt = 0; mt < 4; ++mt)
#pragma unroll
        for (int nt = 0; nt < 6; ++nt)
          acc[mt][nt] = __builtin_amdgcn_mfma_f32_16x16x32_bf16(
              af[mt], bf[nt], acc[mt][nt], 0, 0, 0);
    }
  }

  const int b = row0 >> 8;
  const int t0 = row0 & 255;
  __syncthreads();  // all fragment reads done; Ts (alias) safe to write

  // Epilogue: cols 0-63 = q, 64-127 = k, 128-191 = v (tz uniform per (w,nt)).
#pragma unroll
  for (int nt = 0; nt < 6; ++nt) {
    const int c0 = wn + nt * 16;
    const int tz = c0 >> 6;
    const int d = (c0 & 63) + ln;
#pragma unroll
    for (int mt = 0; mt < 4; ++mt) {
#pragma unroll
      for (int r = 0; r < 4; ++r) {
        const int tl = wm + mt * 16 + qd * 4 + r;  // 0..127
        const u16 val = f2b(acc[mt][nt][r]);
        if (tz == 0)
          q[(((size_t)b * H_NUM + h) * T_DIM + t0 + tl) * HS + d] = val;
        else if (tz == 1)
          k[(((size_t)b * H_NUM + h) * T_DIM + t0 + tl) * HS + d] = val;
        else
          Ts[d * 136 + tl] = val;  // stride 136 -> ~2-way banks (free)
      }
    }
  }
  __syncthreads();
  // vT copy-out, 16B coalesced: vt[d][t0..t0+128)
#pragma unroll
  for (int it = 0; it < 4; ++it) {
    const int idx = it * 256 + tid;
    const int d_l = idx >> 4, tc = idx & 15;
    *(uint4*)&vT[(((size_t)b * H_NUM + h) * HS + d_l) * T_DIM + t0 + tc * 8] =
        *(const uint4*)&Ts[d_l * 136 + tc * 8];
  }
}

// ---------------------------------------------------------------------------
// Kernel B: MFMA flash attention (round-3 verified, unchanged).
// ---------------------------------------------------------------------------
template <bool DIAG>
__device__ __forceinline__ void attn_chunk(int c, int mt, int lane, int ln,
                                           int qd, const bf16x8* qf,
                                           const u16* Kls, u16* Pw,
                                           const u16* vTg, floatx4* oacc,
                                           float* lsum) {
  floatx4 sacc[4];
#pragma unroll
  for (int st = 0; st < 4; ++st) {
    sacc[st] = floatx4{0.f, 0.f, 0.f, 0.f};
#pragma unroll
    for (int kc = 0; kc < 2; ++kc) {
      bf16x8 kf = *(const bf16x8*)&Kls[((c * 4 + st) * 2 + kc) * 512 + lane * 8];
      sacc[st] =
          __builtin_amdgcn_mfma_f32_16x16x32_bf16(qf[kc], kf, sacc[st], 0, 0, 0);
    }
  }
#pragma unroll
  for (int st = 0; st < 4; ++st) {
#pragma unroll
    for (int r = 0; r < 4; ++r) {
      const float sv = sacc[st][r] * 0.125f;
      float p = __expf(sv);
      if (DIAG) {
        const bool ok = (c * 64 + st * 16 + ln) <= (mt * 16 + qd * 4 + r);
        p = ok ? p : 0.f;
      }
      lsum[r] += p;
      Pw[(qd * 4 + r) * 72 + st * 16 + ln] = f2b(p);
    }
  }
#pragma unroll
  for (int kc2 = 0; kc2 < 2; ++kc2) {
    bf16x8 pf = *(const bf16x8*)&Pw[ln * 72 + kc2 * 32 + qd * 8];
#pragma unroll
    for (int dt = 0; dt < 4; ++dt) {
      bf16x8 vf = *(const bf16x8*)(vTg + (dt * 16 + ln) * 256 + c * 64 +
                                   kc2 * 32 + qd * 8);
      oacc[dt] =
          __builtin_amdgcn_mfma_f32_16x16x32_bf16(pf, vf, oacc[dt], 0, 0, 0);
    }
  }
}

__global__ __launch_bounds__(256) void attn_mfma(
    const u16* __restrict__ q, const u16* __restrict__ k,
    const u16* __restrict__ vT, u16* __restrict__ y) {
  __shared__ u16 Kls[32 * 512];   // 32 KB, fragment-major
  __shared__ u16 Pls[4 * 1152];   // per-wave P [16][72] bf16
  const int bh = blockIdx.x;
  const int b = bh / H_NUM, h = bh % H_NUM;
  const int tid = threadIdx.x, lane = tid & 63, w = tid >> 6;
  const int ln = lane & 15, qd = lane >> 4;
  const u16* qg = q + (size_t)bh * (T_DIM * HS);
  const u16* kg = k + (size_t)bh * (T_DIM * HS);
  const u16* vTg = vT + (size_t)bh * (HS * T_DIM);
  u16* Pw = Pls + w * 1152;

#pragma unroll
  for (int ff = 0; ff < 8; ++ff) {
    const int fid = w * 8 + ff;
    const int S16 = fid >> 1, kc = fid & 1;
    gload_lds16(kg + (S16 * 16 + ln) * 64 + kc * 32 + qd * 8, &Kls[fid * 512]);
  }
  __syncthreads();

#pragma unroll
  for (int i = 0; i < 4; ++i) {
    const int mt = i * 4 + w;
    bf16x8 qf[2];
#pragma unroll
    for (int kc = 0; kc < 2; ++kc)
      qf[kc] = *(const bf16x8*)(qg + (mt * 16 + ln) * 64 + kc * 32 + qd * 8);

    floatx4 oacc[4];
    float lsum[4];
#pragma unroll
    for (int dt = 0; dt < 4; ++dt) oacc[dt] = floatx4{0.f, 0.f, 0.f, 0.f};
#pragma unroll
    for (int r = 0; r < 4; ++r) lsum[r] = 0.f;

    const int cmax = mt >> 2;
    for (int c = 0; c < cmax; ++c)
      attn_chunk<false>(c, mt, lane, ln, qd, qf, Kls, Pw, vTg, oacc, lsum);
    attn_chunk<true>(cmax, mt, lane, ln, qd, qf, Kls, Pw, vTg, oacc, lsum);

#pragma unroll
    for (int off = 1; off < 16; off <<= 1)
#pragma unroll
      for (int r = 0; r < 4; ++r) lsum[r] += __shfl_xor(lsum[r], off);

#pragma unroll
    for (int r = 0; r < 4; ++r) {
      const float inv = 1.f / lsum[r];
      const int t = mt * 16 + qd * 4 + r;
      u16* yo = y + ((size_t)b * T_DIM + t) * C_DIM + h * HS;
#pragma unroll
      for (int dt = 0; dt < 4; ++dt) yo[dt * 16 + ln] = f2b(oacc[dt][r] * inv);
    }
  }
}

// ---------------------------------------------------------------------------
// Kernel C: output projection via MFMA (round-3 verified, unchanged).
// ---------------------------------------------------------------------------
__global__ __launch_bounds__(256) void proj_gemm(
    const u16* __restrict__ yb, const u16* __restrict__ Wpt,
    const float* __restrict__ bp, float* __restrict__ out) {
  __shared__ u16 As[128 * 64];
  __shared__ u16 Bs[128 * 64];
  const int row0 = blockIdx.x * 128;
  const int n0 = blockIdx.y * 128;
  const u16* a_rows = yb + (size_t)row0 * C_DIM;
  const u16* bt_rows = Wpt + (size_t)n0 * C_DIM;

  const int tid = threadIdx.x;
  const int lane = tid & 63;
  const int w = tid >> 6;
  const int lr = lane >> 3;
  const int lkc = (lane & 7) * 8;
  const int qd = lane >> 4;
  const int ln = lane & 15;
  const int mw = (w >> 1) * 64;
  const int nw = (w & 1) * 64;

  floatx4 acc[4][4];
#pragma unroll
  for (int i = 0; i < 4; ++i)
#pragma unroll
    for (int j = 0; j < 4; ++j) acc[i][j] = floatx4{0.f, 0.f, 0.f, 0.f};

  for (int kb = 0; kb < C_DIM / 64; ++kb) {
    const int k0 = kb * 64;
    __syncthreads();
#pragma unroll
    for (int s = 0; s < 4; ++s) {
      const int rbase = (s * 4 + w) * 8;
      gload_lds16(a_rows + (size_t)(rbase + lr) * C_DIM + k0 + lkc,
                  As + rbase * 64);
      gload_lds16(bt_rows + (size_t)(rbase + lr) * C_DIM + k0 + lkc,
                  Bs + rbase * 64);
    }
    __syncthreads();

#pragma unroll
    for (int kk = 0; kk < 2; ++kk) {
      bf16x8 af[4], bf[4];
#pragma unroll
      for (int mt = 0; mt < 4; ++mt)
        af[mt] = *(const bf16x8*)&As[(mw + mt * 16 + ln) * 64 + kk * 32 + qd * 8];
#pragma unroll
      for (int nt = 0; nt < 4; ++nt)
        bf[nt] = *(const bf16x8*)&Bs[(nw + nt * 16 + ln) * 64 + kk * 32 + qd * 8];
#pragma unroll
      for (int mt = 0; mt < 4; ++mt)
#pragma unroll
        for (int nt = 0; nt < 4; ++nt)
          acc[mt][nt] = __builtin_amdgcn_mfma_f32_16x16x32_bf16(
              af[mt], bf[nt], acc[mt][nt], 0, 0, 0);
    }
  }

#pragma unroll
  for (int nt = 0; nt < 4; ++nt) {
    const int col = n0 + nw + nt * 16 + ln;
    const float bias = bp[col];
#pragma unroll
    for (int mt = 0; mt < 4; ++mt) {
#pragma unroll
      for (int r = 0; r < 4; ++r) {
        const int grow = row0 + mw + mt * 16 + qd * 4 + r;
        out[(size_t)grow * C_DIM + col] = acc[mt][nt][r] + bias;
      }
    }
  }
}

// ---------------------------------------------------------------------------
extern "C" void kernel_launch(void* const* d_in, const int* in_sizes, int n_in,
                              void* d_out, int out_size, void* d_ws, size_t ws_size,
                              hipStream_t stream) {
  const float* x  = (const float*)d_in[0];
  const float* Wq = (const float*)d_in[1];
  const float* Wk = (const float*)d_in[2];
  const float* Wv = (const float*)d_in[3];
  const float* Wp = (const float*)d_in[4];
  const float* bp = (const float*)d_in[5];
  float* out = (float*)d_out;

  const size_t n_x = (size_t)NROWS * C_DIM;                     // 12,582,912
  const size_t qkv_elems = (size_t)B_DIM * H_NUM * T_DIM * HS;  // 12,582,912

  u16* Wh  = (u16*)d_ws;                    // [6][192][384]
  u16* Wpt = Wh + (size_t)H_NUM * 192 * C_DIM;
  u16* xb  = Wpt + C_DIM * C_DIM;           // [32768][384] bf16
  u16* q   = xb + n_x;                      // [bh][t][d]
  u16* k   = q + qkv_elems;                 // [bh][t][d]
  u16* vT  = k + qkv_elems;                 // [bh][d][t]
  u16* y   = xb;  // alias: xb dead after qkv_gemm
  // ws: 1.2 + 25.2 + 75.5 = ~102 MB

  prep_kernel<<<6144 + 2304, 256, 0, stream>>>(x, Wq, Wk, Wv, Wp, xb, Wh, Wpt);
  qkv_gemm<<<dim3(NROWS / 128, H_NUM), 256, 0, stream>>>(xb, Wh, q, k, vT);
  attn_mfma<<<B_DIM * H_NUM, 256, 0, stream>>>(q, k, vT, y);
  proj_gemm<<<dim3(NROWS / 128, 3), 256, 0, stream>>>(y, Wpt, bp, out);
}

// Round 2
// 199.836 us; speedup vs baseline: 1.1229x; 1.1229x over previous
//
#include <hip/hip_runtime.h>
#include <hip/hip_bf16.h>

#define C_DIM 384
#define H_NUM 6
#define HS    64
#define B_DIM 128
#define T_DIM 256
#define NROWS (B_DIM * T_DIM)  // 32768

typedef unsigned short u16;
typedef unsigned int u32;
typedef short bf16x8 __attribute__((ext_vector_type(8)));
typedef float floatx4 __attribute__((ext_vector_type(4)));

__device__ __forceinline__ u16 f2b(float f) {
  __hip_bfloat16 h = __float2bfloat16(f);
  u16 u;
  __builtin_memcpy(&u, &h, 2);
  return u;
}
// async global->LDS, 16B per lane. LDS dest is wave-uniform base + lane*16.
__device__ __forceinline__ void gload_lds16(const void* g, void* lds) {
  __builtin_amdgcn_global_load_lds(
      (const __attribute__((address_space(1))) u32*)g,
      (__attribute__((address_space(3))) u32*)lds, 16, 0, 0);
}

// ---------------------------------------------------------------------------
// Prep (unchanged, verified): x fp32 -> bf16 xb AND weights -> bf16.
// ---------------------------------------------------------------------------
__global__ __launch_bounds__(256) void prep_kernel(
    const float* __restrict__ x, const float* __restrict__ Wq,
    const float* __restrict__ Wk, const float* __restrict__ Wv,
    const float* __restrict__ Wp, u16* __restrict__ xb,
    u16* __restrict__ Wh, u16* __restrict__ Wpt) {
  const int bid = blockIdx.x;
  const int tid = threadIdx.x;
  if (bid < 6144) {
    const int i = bid * 256 + tid;
    const float4 f0 = ((const float4*)x)[i * 2];
    const float4 f1 = ((const float4*)x)[i * 2 + 1];
    bf16x8 pk;
    pk[0] = (short)f2b(f0.x); pk[1] = (short)f2b(f0.y);
    pk[2] = (short)f2b(f0.z); pk[3] = (short)f2b(f0.w);
    pk[4] = (short)f2b(f1.x); pk[5] = (short)f2b(f1.y);
    pk[6] = (short)f2b(f1.z); pk[7] = (short)f2b(f1.w);
    ((bf16x8*)xb)[i] = pk;
  } else {
    const int idx = (bid - 6144) * 256 + tid;
    const int WHN = H_NUM * 192 * C_DIM;  // 442368
    if (idx < WHN) {
      int h = idx / (192 * C_DIM);
      int rem = idx % (192 * C_DIM);
      int r = rem / C_DIM, c = rem % C_DIM;
      int tz = r >> 6, d = r & 63;
      const float* W = (tz == 0) ? Wq : (tz == 1) ? Wk : Wv;
      Wh[idx] = f2b(W[((size_t)h * C_DIM + c) * HS + d]);
    } else {
      int j = idx - WHN;
      int n = j / C_DIM, c = j % C_DIM;
      Wpt[j] = f2b(Wp[c * C_DIM + n]);
    }
  }
}

// ---------------------------------------------------------------------------
// FUSED kernel: per-(b,h) block. 512 threads = 8 waves.
// Phase 1: GEMM 256x192x384 (q|k|v), m97-style async staging, wave tile 64x96.
// Phase 2: epilogue scatters q->qS(linear LDS), k->Kls(fragment-major LDS),
//          v->vTS([d][t] LDS, XOR-swizzled). NO HBM intermediates.
// Phase 3: causal flash attention from LDS. Wave w handles mt {w, 15-w}
//          (exactly 5 chunks each -> perfect balance). Writes y only.
// LDS map (u16 offsets):
//   [0,16384)      As[256][64]  -> qS[256][64]
//   [16384,28672)  Bs[192][64]  -> Kls[32][512] (Kls extends to 32768)
//   [32768,49152)  vTS[64][256] (col ^ ((d&7)<<3) swizzle)
//   [49152,58368)  Pls: 8 waves x [16][72]
// Total 116736 B.
// ---------------------------------------------------------------------------
#define QS_OFF  0
#define KLS_OFF 16384
#define VTS_OFF 32768
#define PLS_OFF 49152

template <bool DIAG>
__device__ __forceinline__ void attn_chunk_f(int c, int mt, int lane, int ln,
                                             int qd, const bf16x8* qf,
                                             const u16* smem, u16* Pw,
                                             floatx4* oacc, float* lsum) {
  floatx4 sacc[4];
#pragma unroll
  for (int st = 0; st < 4; ++st) {
    sacc[st] = floatx4{0.f, 0.f, 0.f, 0.f};
#pragma unroll
    for (int kc = 0; kc < 2; ++kc) {
      bf16x8 kf = *(const bf16x8*)&smem[KLS_OFF + ((c * 4 + st) * 2 + kc) * 512 +
                                        lane * 8];
      sacc[st] =
          __builtin_amdgcn_mfma_f32_16x16x32_bf16(qf[kc], kf, sacc[st], 0, 0, 0);
    }
  }
#pragma unroll
  for (int st = 0; st < 4; ++st) {
#pragma unroll
    for (int r = 0; r < 4; ++r) {
      const float sv = sacc[st][r] * 0.125f;
      float p = __expf(sv);
      if (DIAG) {
        const bool ok = (c * 64 + st * 16 + ln) <= (mt * 16 + qd * 4 + r);
        p = ok ? p : 0.f;
      }
      lsum[r] += p;
      Pw[(qd * 4 + r) * 72 + st * 16 + ln] = f2b(p);
    }
  }
#pragma unroll
  for (int kc2 = 0; kc2 < 2; ++kc2) {
    bf16x8 pf = *(const bf16x8*)&Pw[ln * 72 + kc2 * 32 + qd * 8];
#pragma unroll
    for (int dt = 0; dt < 4; ++dt) {
      // vTS row = dt*16+ln, col = c*64 + kc2*32 + qd*8; swizzled by (ln&7)<<3
      bf16x8 vf = *(const bf16x8*)&smem[VTS_OFF + (dt * 16 + ln) * 256 +
                                        ((c * 64 + kc2 * 32 + qd * 8) ^
                                         ((ln & 7) << 3))];
      oacc[dt] =
          __builtin_amdgcn_mfma_f32_16x16x32_bf16(pf, vf, oacc[dt], 0, 0, 0);
    }
  }
}

__global__ __launch_bounds__(512) void qkv_attn_fused(
    const u16* __restrict__ xb, const u16* __restrict__ Wh,
    u16* __restrict__ y) {
  __shared__ __align__(16) u16 smem[58368];  // 116736 B
  const int b = blockIdx.x;
  const int h = blockIdx.y;
  const u16* a_rows = xb + (size_t)b * 256 * C_DIM;
  const u16* wbase = Wh + (size_t)h * 192 * C_DIM;

  const int tid = threadIdx.x;
  const int lane = tid & 63;
  const int w = tid >> 6;          // 0..7
  const int lr = lane >> 3;        // staging row within 8-row strip
  const int lkc = (lane & 7) * 8;  // staging col (u16)
  const int qd = lane >> 4;
  const int ln = lane & 15;
  const int wm = (w >> 1) * 64;    // GEMM row group (0,64,128,192)
  const int wn = (w & 1) * 96;     // GEMM col group (0,96)

  // ---------------- Phase 1: GEMM ----------------
  floatx4 acc[4][6];
#pragma unroll
  for (int i = 0; i < 4; ++i)
#pragma unroll
    for (int j = 0; j < 6; ++j) acc[i][j] = floatx4{0.f, 0.f, 0.f, 0.f};

  for (int kb = 0; kb < C_DIM / 64; ++kb) {
    const int k0 = kb * 64;
    __syncthreads();
    // A: 32 strips of 8 rows / 8 waves = 4 per wave
#pragma unroll
    for (int s = 0; s < 4; ++s) {
      const int rbase = (s * 8 + w) * 8;
      gload_lds16(a_rows + (size_t)(rbase + lr) * C_DIM + k0 + lkc,
                  smem + rbase * 64);
    }
    // B: 24 strips of 8 rows / 8 waves = 3 per wave
#pragma unroll
    for (int s = 0; s < 3; ++s) {
      const int rbase = (s * 8 + w) * 8;
      gload_lds16(wbase + (size_t)(rbase + lr) * C_DIM + k0 + lkc,
                  smem + KLS_OFF + rbase * 64);
    }
    __syncthreads();

#pragma unroll
    for (int kk = 0; kk < 2; ++kk) {
      bf16x8 af[4], bf[6];
#pragma unroll
      for (int mt = 0; mt < 4; ++mt)
        af[mt] =
            *(const bf16x8*)&smem[(wm + mt * 16 + ln) * 64 + kk * 32 + qd * 8];
#pragma unroll
      for (int nt = 0; nt < 6; ++nt)
        bf[nt] = *(const bf16x8*)&smem[KLS_OFF + (wn + nt * 16 + ln) * 64 +
                                       kk * 32 + qd * 8];
#pragma unroll
      for (int mt = 0; mt < 4; ++mt)
#pragma unroll
        for (int nt = 0; nt < 6; ++nt)
          acc[mt][nt] = __builtin_amdgcn_mfma_f32_16x16x32_bf16(
              af[mt], bf[nt], acc[mt][nt], 0, 0, 0);
    }
  }
  __syncthreads();  // all staged reads consumed; safe to overwrite As/Bs

  // ---------------- Phase 2: epilogue scatter to LDS ----------------
  // C/D layout: col = c0 + ln, row t = wm + mt*16 + qd*4 + r.
#pragma unroll
  for (int nt = 0; nt < 6; ++nt) {
    const int c0 = wn + nt * 16;  // wave-uniform
#pragma unroll
    for (int mt = 0; mt < 4; ++mt) {
#pragma unroll
      for (int r = 0; r < 4; ++r) {
        const int t = wm + mt * 16 + qd * 4 + r;
        const u16 val = f2b(acc[mt][nt][r]);
        if (c0 < 64) {  // q -> linear [t][d]
          smem[QS_OFF + t * 64 + c0 + ln] = val;
        } else if (c0 < 128) {  // k -> fragment-major Kls
          const int d = c0 - 64 + ln;
          smem[KLS_OFF + ((t >> 4) << 10) + ((d >> 5) << 9) +
               (((d >> 3) & 3) << 7) + ((t & 15) << 3) + (d & 7)] = val;
        } else {  // v -> vTS [d][t], XOR-swizzled col
          const int dv = c0 - 128 + ln;
          smem[VTS_OFF + dv * 256 + (t ^ ((dv & 7) << 3))] = val;
        }
      }
    }
  }
  __syncthreads();

  // ---------------- Phase 3: causal flash attention ----------------
  u16* Pw = smem + PLS_OFF + w * 1152;
#pragma unroll
  for (int i = 0; i < 2; ++i) {
    const int mt = i ? (15 - w) : w;
    bf16x8 qf[2];
#pragma unroll
    for (int kc = 0; kc < 2; ++kc)
      qf[kc] = *(const bf16x8*)&smem[QS_OFF + (mt * 16 + ln) * 64 + kc * 32 +
                                     qd * 8];

    floatx4 oacc[4];
    float lsum[4];
#pragma unroll
    for (int dt = 0; dt < 4; ++dt) oacc[dt] = floatx4{0.f, 0.f, 0.f, 0.f};
#pragma unroll
    for (int r = 0; r < 4; ++r) lsum[r] = 0.f;

    const int cmax = mt >> 2;
    for (int c = 0; c < cmax; ++c)
      attn_chunk_f<false>(c, mt, lane, ln, qd, qf, smem, Pw, oacc, lsum);
    attn_chunk_f<true>(cmax, mt, lane, ln, qd, qf, smem, Pw, oacc, lsum);

#pragma unroll
    for (int off = 1; off < 16; off <<= 1)
#pragma unroll
      for (int r = 0; r < 4; ++r) lsum[r] += __shfl_xor(lsum[r], off);

#pragma unroll
    for (int r = 0; r < 4; ++r) {
      const float inv = 1.f / lsum[r];
      const int t = mt * 16 + qd * 4 + r;
      u16* yo = y + ((size_t)b * T_DIM + t) * C_DIM + h * HS;
#pragma unroll
      for (int dt = 0; dt < 4; ++dt) yo[dt * 16 + ln] = f2b(oacc[dt][r] * inv);
    }
  }
}

// ---------------------------------------------------------------------------
// Kernel C: output projection via MFMA (unchanged, verified).
// ---------------------------------------------------------------------------
__global__ __launch_bounds__(256) void proj_gemm(
    const u16* __restrict__ yb, const u16* __restrict__ Wpt,
    const float* __restrict__ bp, float* __restrict__ out) {
  __shared__ u16 As[128 * 64];
  __shared__ u16 Bs[128 * 64];
  const int row0 = blockIdx.x * 128;
  const int n0 = blockIdx.y * 128;
  const u16* a_rows = yb + (size_t)row0 * C_DIM;
  const u16* bt_rows = Wpt + (size_t)n0 * C_DIM;

  const int tid = threadIdx.x;
  const int lane = tid & 63;
  const int w = tid >> 6;
  const int lr = lane >> 3;
  const int lkc = (lane & 7) * 8;
  const int qd = lane >> 4;
  const int ln = lane & 15;
  const int mw = (w >> 1) * 64;
  const int nw = (w & 1) * 64;

  floatx4 acc[4][4];
#pragma unroll
  for (int i = 0; i < 4; ++i)
#pragma unroll
    for (int j = 0; j < 4; ++j) acc[i][j] = floatx4{0.f, 0.f, 0.f, 0.f};

  for (int kb = 0; kb < C_DIM / 64; ++kb) {
    const int k0 = kb * 64;
    __syncthreads();
#pragma unroll
    for (int s = 0; s < 4; ++s) {
      const int rbase = (s * 4 + w) * 8;
      gload_lds16(a_rows + (size_t)(rbase + lr) * C_DIM + k0 + lkc,
                  As + rbase * 64);
      gload_lds16(bt_rows + (size_t)(rbase + lr) * C_DIM + k0 + lkc,
                  Bs + rbase * 64);
    }
    __syncthreads();

#pragma unroll
    for (int kk = 0; kk < 2; ++kk) {
      bf16x8 af[4], bf[4];
#pragma unroll
      for (int mt = 0; mt < 4; ++mt)
        af[mt] = *(const bf16x8*)&As[(mw + mt * 16 + ln) * 64 + kk * 32 + qd * 8];
#pragma unroll
      for (int nt = 0; nt < 4; ++nt)
        bf[nt] = *(const bf16x8*)&Bs[(nw + nt * 16 + ln) * 64 + kk * 32 + qd * 8];
#pragma unroll
      for (int mt = 0; mt < 4; ++mt)
#pragma unroll
        for (int nt = 0; nt < 4; ++nt)
          acc[mt][nt] = __builtin_amdgcn_mfma_f32_16x16x32_bf16(
              af[mt], bf[nt], acc[mt][nt], 0, 0, 0);
    }
  }

#pragma unroll
  for (int nt = 0; nt < 4; ++nt) {
    const int col = n0 + nw + nt * 16 + ln;
    const float bias = bp[col];
#pragma unroll
    for (int mt = 0; mt < 4; ++mt) {
#pragma unroll
      for (int r = 0; r < 4; ++r) {
        const int grow = row0 + mw + mt * 16 + qd * 4 + r;
        out[(size_t)grow * C_DIM + col] = acc[mt][nt][r] + bias;
      }
    }
  }
}

// ---------------------------------------------------------------------------
extern "C" void kernel_launch(void* const* d_in, const int* in_sizes, int n_in,
                              void* d_out, int out_size, void* d_ws, size_t ws_size,
                              hipStream_t stream) {
  const float* x  = (const float*)d_in[0];
  const float* Wq = (const float*)d_in[1];
  const float* Wk = (const float*)d_in[2];
  const float* Wv = (const float*)d_in[3];
  const float* Wp = (const float*)d_in[4];
  const float* bp = (const float*)d_in[5];
  float* out = (float*)d_out;

  const size_t n_x = (size_t)NROWS * C_DIM;  // 12,582,912

  u16* Wh  = (u16*)d_ws;                    // [6][192][384]
  u16* Wpt = Wh + (size_t)H_NUM * 192 * C_DIM;
  u16* xb  = Wpt + C_DIM * C_DIM;           // [32768][384] bf16
  u16* y   = xb + n_x;                      // [32768][384] bf16 (own buffer:
                                            // xb is still live during fused)
  // ws: ~1.2 + 24 + 24 = ~50 MB

  prep_kernel<<<6144 + 2304, 256, 0, stream>>>(x, Wq, Wk, Wv, Wp, xb, Wh, Wpt);
  qkv_attn_fused<<<dim3(B_DIM, H_NUM), 512, 0, stream>>>(xb, Wh, y);
  proj_gemm<<<dim3(NROWS / 128, 3), 256, 0, stream>>>(y, Wpt, bp, out);
}

// Round 3
// 191.868 us; speedup vs baseline: 1.1695x; 1.0415x over previous
//
#include <hip/hip_runtime.h>
#include <hip/hip_bf16.h>

#define C_DIM 384
#define H_NUM 6
#define HS    64
#define B_DIM 128
#define T_DIM 256
#define NROWS (B_DIM * T_DIM)  // 32768

typedef unsigned short u16;
typedef unsigned int u32;
typedef short bf16x8 __attribute__((ext_vector_type(8)));
typedef float floatx4 __attribute__((ext_vector_type(4)));

__device__ __forceinline__ u16 f2b(float f) {
  __hip_bfloat16 h = __float2bfloat16(f);
  u16 u;
  __builtin_memcpy(&u, &h, 2);
  return u;
}
// async global->LDS, 16B per lane. LDS dest is wave-uniform base + lane*16.
__device__ __forceinline__ void gload_lds16(const void* g, void* lds) {
  __builtin_amdgcn_global_load_lds(
      (const __attribute__((address_space(1))) u32*)g,
      (__attribute__((address_space(3))) u32*)lds, 16, 0, 0);
}

// ---------------------------------------------------------------------------
// Prep (weights only now): fp32 -> bf16 with K-dim XOR pre-permutation so the
// GEMM's linear DMA staging + XOR'd ds_read is conflict-free (rule 21:
// linear DMA dest + inverse-permuted source + swizzled read).
// Wh  [h][192][384]: row r = [Wq^T;Wk^T;Wv^T], col c permuted within each
//                    64-block: source col = c ^ ((r&7)<<3).
// Wpt [n=384][c=384]: source col = c ^ ((n&7)<<3).
// ---------------------------------------------------------------------------
__global__ __launch_bounds__(256) void prep_w(
    const float* __restrict__ Wq, const float* __restrict__ Wk,
    const float* __restrict__ Wv, const float* __restrict__ Wp,
    u16* __restrict__ Wh, u16* __restrict__ Wpt) {
  const int idx = blockIdx.x * 256 + threadIdx.x;  // grid 2304 -> 589824
  const int WHN = H_NUM * 192 * C_DIM;             // 442368
  if (idx < WHN) {
    int h = idx / (192 * C_DIM);
    int rem = idx % (192 * C_DIM);
    int r = rem / C_DIM, c = rem % C_DIM;
    int tz = r >> 6, d = r & 63;
    const int cs = c ^ ((r & 7) << 3);  // XOR only touches bits 3-5 (<64)
    const float* W = (tz == 0) ? Wq : (tz == 1) ? Wk : Wv;
    Wh[idx] = f2b(W[((size_t)h * C_DIM + cs) * HS + d]);
  } else {
    int j = idx - WHN;
    int n = j / C_DIM, c = j % C_DIM;
    const int cs = c ^ ((n & 7) << 3);
    Wpt[j] = f2b(Wp[cs * C_DIM + n]);
  }
}

// ---------------------------------------------------------------------------
// FUSED kernel: per-(b,h) block. 512 threads = 8 waves.
// Phase 1: GEMM 256x192x384. A (=x) read fp32 directly from global into regs,
//          cvt->bf16, ds_write XOR-swizzled (conflict-free write+read).
//          Next K-tile's A loads issued after barrier -> hidden under MFMA.
//          B DMA'd from pre-permuted Wh, read with same XOR.
// Phase 2: epilogue scatters q->qS(linear), k->Kls(fragment-major),
//          v->vTS([d][t], XOR-swizzled). No HBM intermediates.
// Phase 3: causal flash attention from LDS. Wave w handles mt {w, 15-w}.
//          y written with per-head-block col permutation (c ^ ((t&7)<<3))
//          so proj_gemm's DMA staging + XOR'd read is conflict-free.
// LDS map (u16 offsets):
//   [0,16384)      As[256][64] (GEMM, swizzled)  -> qS[256][64] (attn, linear)
//   [16384,28672)  Bs[192][64] -> Kls[32][512] (extends to 32768)
//   [32768,49152)  vTS[64][256] (col ^ ((d&7)<<3))
//   [49152,58368)  Pls: 8 waves x [16][72]
// ---------------------------------------------------------------------------
#define QS_OFF  0
#define KLS_OFF 16384
#define VTS_OFF 32768
#define PLS_OFF 49152

template <bool DIAG>
__device__ __forceinline__ void attn_chunk_f(int c, int mt, int lane, int ln,
                                             int qd, const bf16x8* qf,
                                             const u16* smem, u16* Pw,
                                             floatx4* oacc, float* lsum) {
  floatx4 sacc[4];
#pragma unroll
  for (int st = 0; st < 4; ++st) {
    sacc[st] = floatx4{0.f, 0.f, 0.f, 0.f};
#pragma unroll
    for (int kc = 0; kc < 2; ++kc) {
      bf16x8 kf = *(const bf16x8*)&smem[KLS_OFF + ((c * 4 + st) * 2 + kc) * 512 +
                                        lane * 8];
      sacc[st] =
          __builtin_amdgcn_mfma_f32_16x16x32_bf16(qf[kc], kf, sacc[st], 0, 0, 0);
    }
  }
#pragma unroll
  for (int st = 0; st < 4; ++st) {
#pragma unroll
    for (int r = 0; r < 4; ++r) {
      const float sv = sacc[st][r] * 0.125f;
      float p = __expf(sv);
      if (DIAG) {
        const bool ok = (c * 64 + st * 16 + ln) <= (mt * 16 + qd * 4 + r);
        p = ok ? p : 0.f;
      }
      lsum[r] += p;
      Pw[(qd * 4 + r) * 72 + st * 16 + ln] = f2b(p);
    }
  }
#pragma unroll
  for (int kc2 = 0; kc2 < 2; ++kc2) {
    bf16x8 pf = *(const bf16x8*)&Pw[ln * 72 + kc2 * 32 + qd * 8];
#pragma unroll
    for (int dt = 0; dt < 4; ++dt) {
      bf16x8 vf = *(const bf16x8*)&smem[VTS_OFF + (dt * 16 + ln) * 256 +
                                        ((c * 64 + kc2 * 32 + qd * 8) ^
                                         ((ln & 7) << 3))];
      oacc[dt] =
          __builtin_amdgcn_mfma_f32_16x16x32_bf16(pf, vf, oacc[dt], 0, 0, 0);
    }
  }
}

#define A_ISSUE(K0)                                                     \
  {                                                                     \
    _Pragma("unroll") for (int u = 0; u < 4; ++u) {                     \
      const int idx_ = u * 512 + tid;                                   \
      const int row_ = idx_ >> 3, c8_ = (idx_ & 7) * 8;                 \
      const float* p_ = xg + (size_t)row_ * C_DIM + (K0) + c8_;         \
      ar[2 * u] = *(const float4*)p_;                                   \
      ar[2 * u + 1] = *(const float4*)(p_ + 4);                         \
    }                                                                   \
  }

__global__ __launch_bounds__(512) void qkv_attn_fused(
    const float* __restrict__ x, const u16* __restrict__ Wh,
    u16* __restrict__ y) {
  __shared__ __align__(16) u16 smem[58368];  // 116736 B
  const int b = blockIdx.x;
  const int h = blockIdx.y;
  const float* xg = x + (size_t)b * 256 * C_DIM;
  const u16* wbase = Wh + (size_t)h * 192 * C_DIM;

  const int tid = threadIdx.x;
  const int lane = tid & 63;
  const int w = tid >> 6;          // 0..7
  const int lr = lane >> 3;        // DMA staging row within 8-row strip
  const int lkc = (lane & 7) * 8;  // DMA staging col (u16)
  const int qd = lane >> 4;
  const int ln = lane & 15;
  const int sx = (ln & 7) << 3;    // fragment-read XOR key
  const int wm = (w >> 1) * 64;    // GEMM row group (0,64,128,192)
  const int wn = (w & 1) * 96;     // GEMM col group (0,96)

  // ---------------- Phase 1: GEMM ----------------
  floatx4 acc[4][6];
#pragma unroll
  for (int i = 0; i < 4; ++i)
#pragma unroll
    for (int j = 0; j < 6; ++j) acc[i][j] = floatx4{0.f, 0.f, 0.f, 0.f};

  float4 ar[8];  // A-tile staging regs: 4 units x 8 f32
  A_ISSUE(0);

  for (int kb = 0; kb < 6; ++kb) {
    __syncthreads();  // prev MFMA reads done; LDS writable; ar[] drained
    // A: cvt + swizzled ds_write (conflict-free: 8 rows spread over 8 slots)
#pragma unroll
    for (int u = 0; u < 4; ++u) {
      const int idx_ = u * 512 + tid;
      const int row_ = idx_ >> 3, c8_ = (idx_ & 7) * 8;
      bf16x8 pk;
      pk[0] = (short)f2b(ar[2 * u].x);
      pk[1] = (short)f2b(ar[2 * u].y);
      pk[2] = (short)f2b(ar[2 * u].z);
      pk[3] = (short)f2b(ar[2 * u].w);
      pk[4] = (short)f2b(ar[2 * u + 1].x);
      pk[5] = (short)f2b(ar[2 * u + 1].y);
      pk[6] = (short)f2b(ar[2 * u + 1].z);
      pk[7] = (short)f2b(ar[2 * u + 1].w);
      *(bf16x8*)&smem[QS_OFF + row_ * 64 + (c8_ ^ ((row_ & 7) << 3))] = pk;
    }
    // B: 24 strips of 8 rows / 8 waves = 3 per wave (DMA, pre-permuted Wh)
    const int k0 = kb * 64;
#pragma unroll
    for (int s = 0; s < 3; ++s) {
      const int rbase = (s * 8 + w) * 8;
      gload_lds16(wbase + (size_t)(rbase + lr) * C_DIM + k0 + lkc,
                  smem + KLS_OFF + rbase * 64);
    }
    __syncthreads();  // drains ds_writes + B DMA
    if (kb < 5) A_ISSUE((kb + 1) * 64);  // in flight under MFMA below

#pragma unroll
    for (int kk = 0; kk < 2; ++kk) {
      bf16x8 af[4], bf[6];
#pragma unroll
      for (int mt = 0; mt < 4; ++mt)
        af[mt] = *(const bf16x8*)&smem[QS_OFF + (wm + mt * 16 + ln) * 64 +
                                       ((kk * 32 + qd * 8) ^ sx)];
#pragma unroll
      for (int nt = 0; nt < 6; ++nt)
        bf[nt] = *(const bf16x8*)&smem[KLS_OFF + (wn + nt * 16 + ln) * 64 +
                                       ((kk * 32 + qd * 8) ^ sx)];
#pragma unroll
      for (int mt = 0; mt < 4; ++mt)
#pragma unroll
        for (int nt = 0; nt < 6; ++nt)
          acc[mt][nt] = __builtin_amdgcn_mfma_f32_16x16x32_bf16(
              af[mt], bf[nt], acc[mt][nt], 0, 0, 0);
    }
  }
  __syncthreads();  // all staged reads consumed; safe to overwrite As/Bs

  // ---------------- Phase 2: epilogue scatter to LDS ----------------
  // C/D layout: col = c0 + ln, row t = wm + mt*16 + qd*4 + r.
#pragma unroll
  for (int nt = 0; nt < 6; ++nt) {
    const int c0 = wn + nt * 16;  // wave-uniform
#pragma unroll
    for (int mt = 0; mt < 4; ++mt) {
#pragma unroll
      for (int r = 0; r < 4; ++r) {
        const int t = wm + mt * 16 + qd * 4 + r;
        const u16 val = f2b(acc[mt][nt][r]);
        if (c0 < 64) {  // q -> linear [t][d]
          smem[QS_OFF + t * 64 + c0 + ln] = val;
        } else if (c0 < 128) {  // k -> fragment-major Kls
          const int d = c0 - 64 + ln;
          smem[KLS_OFF + ((t >> 4) << 10) + ((d >> 5) << 9) +
               (((d >> 3) & 3) << 7) + ((t & 15) << 3) + (d & 7)] = val;
        } else {  // v -> vTS [d][t], XOR-swizzled col
          const int dv = c0 - 128 + ln;
          smem[VTS_OFF + dv * 256 + (t ^ ((dv & 7) << 3))] = val;
        }
      }
    }
  }
  __syncthreads();

  // ---------------- Phase 3: causal flash attention ----------------
  u16* Pw = smem + PLS_OFF + w * 1152;
#pragma unroll
  for (int i = 0; i < 2; ++i) {
    const int mt = i ? (15 - w) : w;
    bf16x8 qf[2];
#pragma unroll
    for (int kc = 0; kc < 2; ++kc)
      qf[kc] = *(const bf16x8*)&smem[QS_OFF + (mt * 16 + ln) * 64 + kc * 32 +
                                     qd * 8];

    floatx4 oacc[4];
    float lsum[4];
#pragma unroll
    for (int dt = 0; dt < 4; ++dt) oacc[dt] = floatx4{0.f, 0.f, 0.f, 0.f};
#pragma unroll
    for (int r = 0; r < 4; ++r) lsum[r] = 0.f;

    const int cmax = mt >> 2;
    for (int c = 0; c < cmax; ++c)
      attn_chunk_f<false>(c, mt, lane, ln, qd, qf, smem, Pw, oacc, lsum);
    attn_chunk_f<true>(cmax, mt, lane, ln, qd, qf, smem, Pw, oacc, lsum);

#pragma unroll
    for (int off = 1; off < 16; off <<= 1)
#pragma unroll
      for (int r = 0; r < 4; ++r) lsum[r] += __shfl_xor(lsum[r], off);

    // y written with per-head-block col permutation for proj's swizzled read
#pragma unroll
    for (int r = 0; r < 4; ++r) {
      const float inv = 1.f / lsum[r];
      const int t = mt * 16 + qd * 4 + r;
      const int sy = (t & 7) << 3;
      u16* yo = y + ((size_t)b * T_DIM + t) * C_DIM + h * HS;
#pragma unroll
      for (int dt = 0; dt < 4; ++dt)
        yo[(dt * 16 + ln) ^ sy] = f2b(oacc[dt][r] * inv);
    }
  }
}

// ---------------------------------------------------------------------------
// Kernel C: output projection. Same structure as before + XOR'd fragment
// reads (sources y and Wpt are pre-permuted along K within 64-blocks).
// ---------------------------------------------------------------------------
__global__ __launch_bounds__(256) void proj_gemm(
    const u16* __restrict__ yb, const u16* __restrict__ Wpt,
    const float* __restrict__ bp, float* __restrict__ out) {
  __shared__ u16 As[128 * 64];
  __shared__ u16 Bs[128 * 64];
  const int row0 = blockIdx.x * 128;
  const int n0 = blockIdx.y * 128;
  const u16* a_rows = yb + (size_t)row0 * C_DIM;
  const u16* bt_rows = Wpt + (size_t)n0 * C_DIM;

  const int tid = threadIdx.x;
  const int lane = tid & 63;
  const int w = tid >> 6;
  const int lr = lane >> 3;
  const int lkc = (lane & 7) * 8;
  const int qd = lane >> 4;
  const int ln = lane & 15;
  const int sx = (ln & 7) << 3;
  const int mw = (w >> 1) * 64;
  const int nw = (w & 1) * 64;

  floatx4 acc[4][4];
#pragma unroll
  for (int i = 0; i < 4; ++i)
#pragma unroll
    for (int j = 0; j < 4; ++j) acc[i][j] = floatx4{0.f, 0.f, 0.f, 0.f};

  for (int kb = 0; kb < C_DIM / 64; ++kb) {
    const int k0 = kb * 64;
    __syncthreads();
#pragma unroll
    for (int s = 0; s < 4; ++s) {
      const int rbase = (s * 4 + w) * 8;
      gload_lds16(a_rows + (size_t)(rbase + lr) * C_DIM + k0 + lkc,
                  As + rbase * 64);
      gload_lds16(bt_rows + (size_t)(rbase + lr) * C_DIM + k0 + lkc,
                  Bs + rbase * 64);
    }
    __syncthreads();

#pragma unroll
    for (int kk = 0; kk < 2; ++kk) {
      bf16x8 af[4], bf[4];
#pragma unroll
      for (int mt = 0; mt < 4; ++mt)
        af[mt] = *(const bf16x8*)&As[(mw + mt * 16 + ln) * 64 +
                                     ((kk * 32 + qd * 8) ^ sx)];
#pragma unroll
      for (int nt = 0; nt < 4; ++nt)
        bf[nt] = *(const bf16x8*)&Bs[(nw + nt * 16 + ln) * 64 +
                                     ((kk * 32 + qd * 8) ^ sx)];
#pragma unroll
      for (int mt = 0; mt < 4; ++mt)
#pragma unroll
        for (int nt = 0; nt < 4; ++nt)
          acc[mt][nt] = __builtin_amdgcn_mfma_f32_16x16x32_bf16(
              af[mt], bf[nt], acc[mt][nt], 0, 0, 0);
    }
  }

#pragma unroll
  for (int nt = 0; nt < 4; ++nt) {
    const int col = n0 + nw + nt * 16 + ln;
    const float bias = bp[col];
#pragma unroll
    for (int mt = 0; mt < 4; ++mt) {
#pragma unroll
      for (int r = 0; r < 4; ++r) {
        const int grow = row0 + mw + mt * 16 + qd * 4 + r;
        out[(size_t)grow * C_DIM + col] = acc[mt][nt][r] + bias;
      }
    }
  }
}

// ---------------------------------------------------------------------------
extern "C" void kernel_launch(void* const* d_in, const int* in_sizes, int n_in,
                              void* d_out, int out_size, void* d_ws, size_t ws_size,
                              hipStream_t stream) {
  const float* x  = (const float*)d_in[0];
  const float* Wq = (const float*)d_in[1];
  const float* Wk = (const float*)d_in[2];
  const float* Wv = (const float*)d_in[3];
  const float* Wp = (const float*)d_in[4];
  const float* bp = (const float*)d_in[5];
  float* out = (float*)d_out;

  u16* Wh  = (u16*)d_ws;                       // [6][192][384] (K-permuted)
  u16* Wpt = Wh + (size_t)H_NUM * 192 * C_DIM; // [384][384]   (K-permuted)
  u16* y   = Wpt + C_DIM * C_DIM;              // [32768][384] (col-permuted)
  // ws: ~0.9 + 0.3 + 24 = ~25.2 MB

  prep_w<<<2304, 256, 0, stream>>>(Wq, Wk, Wv, Wp, Wh, Wpt);
  qkv_attn_fused<<<dim3(B_DIM, H_NUM), 512, 0, stream>>>(x, Wh, y);
  proj_gemm<<<dim3(NROWS / 128, 3), 256, 0, stream>>>(y, Wpt, bp, out);
}

// Round 4
// 181.915 us; speedup vs baseline: 1.2335x; 1.0547x over previous
//
#include <hip/hip_runtime.h>
#include <hip/hip_bf16.h>

#define C_DIM 384
#define H_NUM 6
#define HS    64
#define B_DIM 128
#define T_DIM 256
#define NROWS (B_DIM * T_DIM)  // 32768

typedef unsigned short u16;
typedef unsigned int u32;
typedef short bf16x8 __attribute__((ext_vector_type(8)));
typedef float floatx4 __attribute__((ext_vector_type(4)));

__device__ __forceinline__ u16 f2b(float f) {
  __hip_bfloat16 h = __float2bfloat16(f);
  u16 u;
  __builtin_memcpy(&u, &h, 2);
  return u;
}
// async global->LDS, 16B per lane. LDS dest is wave-uniform base + lane*16.
__device__ __forceinline__ void gload_lds16(const void* g, void* lds) {
  __builtin_amdgcn_global_load_lds(
      (const __attribute__((address_space(1))) u32*)g,
      (__attribute__((address_space(3))) u32*)lds, 16, 0, 0);
}

// ---------------------------------------------------------------------------
// Prep: x fp32 -> bf16 xb (K-permuted per row: src col = c ^ ((row&7)<<3))
// AND weights -> bf16 (K-permuted as in round 3).
// All permutations are the rule-21 pattern: linear DMA dest in the consumer +
// inverse-permuted source here + XOR'd fragment read in the consumer.
// ---------------------------------------------------------------------------
__global__ __launch_bounds__(256) void prep_kernel(
    const float* __restrict__ x, const float* __restrict__ Wq,
    const float* __restrict__ Wk, const float* __restrict__ Wv,
    const float* __restrict__ Wp, u16* __restrict__ xb,
    u16* __restrict__ Wh, u16* __restrict__ Wpt) {
  const int bid = blockIdx.x;
  const int tid = threadIdx.x;
  if (bid < 6144) {  // x: 12,582,912 elems = 6144*256 threads x 8
    const int i = bid * 256 + tid;
    const int row = (i * 8) / C_DIM;
    const int c8 = (i * 8) % C_DIM;
    const int cs = c8 ^ ((row & 7) << 3);  // XOR bits 3-5, within 64-block
    const float* p = x + (size_t)row * C_DIM + cs;
    const float4 f0 = *(const float4*)p;
    const float4 f1 = *(const float4*)(p + 4);
    bf16x8 pk;
    pk[0] = (short)f2b(f0.x); pk[1] = (short)f2b(f0.y);
    pk[2] = (short)f2b(f0.z); pk[3] = (short)f2b(f0.w);
    pk[4] = (short)f2b(f1.x); pk[5] = (short)f2b(f1.y);
    pk[6] = (short)f2b(f1.z); pk[7] = (short)f2b(f1.w);
    ((bf16x8*)xb)[i] = pk;
  } else {  // weights: 442368 + 147456 = 589824 = 2304*256
    const int idx = (bid - 6144) * 256 + tid;
    const int WHN = H_NUM * 192 * C_DIM;  // 442368
    if (idx < WHN) {
      int h = idx / (192 * C_DIM);
      int rem = idx % (192 * C_DIM);
      int r = rem / C_DIM, c = rem % C_DIM;
      int tz = r >> 6, d = r & 63;
      const int cs = c ^ ((r & 7) << 3);
      const float* W = (tz == 0) ? Wq : (tz == 1) ? Wk : Wv;
      Wh[idx] = f2b(W[((size_t)h * C_DIM + cs) * HS + d]);
    } else {
      int j = idx - WHN;
      int n = j / C_DIM, c = j % C_DIM;
      const int cs = c ^ ((n & 7) << 3);
      Wpt[j] = f2b(Wp[cs * C_DIM + n]);
    }
  }
}

// ---------------------------------------------------------------------------
// FUSED kernel: per-(b,h) block. 512 threads = 8 waves.
// Phase 1: GEMM 256x192x384, DMA staging (A from permuted xb, B from permuted
//          Wh), DOUBLE-BUFFERED with counted vmcnt(7) — no drain in loop.
// Phase 2: epilogue scatter q/k/v to LDS (no HBM intermediates).
// Phase 3: causal flash attention from LDS; y written col-permuted for proj.
// LDS (u16 offsets): GEMM: AS0=0, AS1=16384, BS0=32768, BS1=45056 (112 KB)
//                    attn: QS=0, KLS=16384, VTS=32768, PLS=49152 (114 KB)
// Total 58368 u16 = 116736 B.
// ---------------------------------------------------------------------------
#define AS0_OFF 0
#define AS1_OFF 16384
#define BS0_OFF 32768
#define BS1_OFF 45056
#define QS_OFF  0
#define KLS_OFF 16384
#define VTS_OFF 32768
#define PLS_OFF 49152

template <bool DIAG>
__device__ __forceinline__ void attn_chunk_f(int c, int mt, int lane, int ln,
                                             int qd, const bf16x8* qf,
                                             const u16* smem, u16* Pw,
                                             floatx4* oacc, float* lsum) {
  floatx4 sacc[4];
#pragma unroll
  for (int st = 0; st < 4; ++st) {
    sacc[st] = floatx4{0.f, 0.f, 0.f, 0.f};
#pragma unroll
    for (int kc = 0; kc < 2; ++kc) {
      bf16x8 kf = *(const bf16x8*)&smem[KLS_OFF + ((c * 4 + st) * 2 + kc) * 512 +
                                        lane * 8];
      sacc[st] =
          __builtin_amdgcn_mfma_f32_16x16x32_bf16(qf[kc], kf, sacc[st], 0, 0, 0);
    }
  }
#pragma unroll
  for (int st = 0; st < 4; ++st) {
#pragma unroll
    for (int r = 0; r < 4; ++r) {
      const float sv = sacc[st][r] * 0.125f;
      float p = __expf(sv);
      if (DIAG) {
        const bool ok = (c * 64 + st * 16 + ln) <= (mt * 16 + qd * 4 + r);
        p = ok ? p : 0.f;
      }
      lsum[r] += p;
      Pw[(qd * 4 + r) * 72 + st * 16 + ln] = f2b(p);
    }
  }
#pragma unroll
  for (int kc2 = 0; kc2 < 2; ++kc2) {
    bf16x8 pf = *(const bf16x8*)&Pw[ln * 72 + kc2 * 32 + qd * 8];
#pragma unroll
    for (int dt = 0; dt < 4; ++dt) {
      bf16x8 vf = *(const bf16x8*)&smem[VTS_OFF + (dt * 16 + ln) * 256 +
                                        ((c * 64 + kc2 * 32 + qd * 8) ^
                                         ((ln & 7) << 3))];
      oacc[dt] =
          __builtin_amdgcn_mfma_f32_16x16x32_bf16(pf, vf, oacc[dt], 0, 0, 0);
    }
  }
}

__global__ __launch_bounds__(512) void qkv_attn_fused(
    const u16* __restrict__ xb, const u16* __restrict__ Wh,
    u16* __restrict__ y) {
  __shared__ __align__(16) u16 smem[58368];  // 116736 B
  const int b = blockIdx.x;
  const int h = blockIdx.y;
  const u16* a_rows = xb + (size_t)b * 256 * C_DIM;
  const u16* wbase = Wh + (size_t)h * 192 * C_DIM;

  const int tid = threadIdx.x;
  const int lane = tid & 63;
  const int w = tid >> 6;          // 0..7
  const int lr = lane >> 3;        // DMA staging row within 8-row strip
  const int lkc = (lane & 7) * 8;  // DMA staging col (u16)
  const int qd = lane >> 4;
  const int ln = lane & 15;
  const int sx = (ln & 7) << 3;    // fragment-read XOR key
  const int wm = (w >> 1) * 64;    // GEMM row group (0,64,128,192)
  const int wn = (w & 1) * 96;     // GEMM col group (0,96)

  // ---------------- Phase 1: GEMM (dbuf, counted vmcnt) ----------------
  floatx4 acc[4][6];
#pragma unroll
  for (int i = 0; i < 4; ++i)
#pragma unroll
    for (int j = 0; j < 6; ++j) acc[i][j] = floatx4{0.f, 0.f, 0.f, 0.f};

  // prologue: stage kb=0 into buf0 (7 DMA issues/thread)
#pragma unroll
  for (int s = 0; s < 4; ++s) {
    const int rbase = (s * 8 + w) * 8;
    gload_lds16(a_rows + (size_t)(rbase + lr) * C_DIM + lkc,
                smem + AS0_OFF + rbase * 64);
  }
#pragma unroll
  for (int s = 0; s < 3; ++s) {
    const int rbase = (s * 8 + w) * 8;
    gload_lds16(wbase + (size_t)(rbase + lr) * C_DIM + lkc,
                smem + BS0_OFF + rbase * 64);
  }

  for (int kb = 0; kb < 6; ++kb) {
    const int pa = (kb & 1) ? AS1_OFF : AS0_OFF;
    const int pb = (kb & 1) ? BS1_OFF : BS0_OFF;
    if (kb < 5) {
      // issue next tile into the other buffers (reads of them ended at the
      // trailing barrier of iter kb-1)
      const int qa = (kb & 1) ? AS0_OFF : AS1_OFF;
      const int qb = (kb & 1) ? BS0_OFF : BS1_OFF;
      const int k0 = (kb + 1) * 64;
#pragma unroll
      for (int s = 0; s < 4; ++s) {
        const int rbase = (s * 8 + w) * 8;
        gload_lds16(a_rows + (size_t)(rbase + lr) * C_DIM + k0 + lkc,
                    smem + qa + rbase * 64);
      }
#pragma unroll
      for (int s = 0; s < 3; ++s) {
        const int rbase = (s * 8 + w) * 8;
        gload_lds16(wbase + (size_t)(rbase + lr) * C_DIM + k0 + lkc,
                    smem + qb + rbase * 64);
      }
      // 14 outstanding; wait the oldest 7 (current tile), keep 7 in flight
      asm volatile("s_waitcnt vmcnt(7)" ::: "memory");
    } else {
      asm volatile("s_waitcnt vmcnt(0)" ::: "memory");
    }
    __builtin_amdgcn_s_barrier();
    __builtin_amdgcn_sched_barrier(0);

#pragma unroll
    for (int kk = 0; kk < 2; ++kk) {
      bf16x8 af[4], bf[6];
#pragma unroll
      for (int mt = 0; mt < 4; ++mt)
        af[mt] = *(const bf16x8*)&smem[pa + (wm + mt * 16 + ln) * 64 +
                                       ((kk * 32 + qd * 8) ^ sx)];
#pragma unroll
      for (int nt = 0; nt < 6; ++nt)
        bf[nt] = *(const bf16x8*)&smem[pb + (wn + nt * 16 + ln) * 64 +
                                       ((kk * 32 + qd * 8) ^ sx)];
#pragma unroll
      for (int mt = 0; mt < 4; ++mt)
#pragma unroll
        for (int nt = 0; nt < 6; ++nt)
          acc[mt][nt] = __builtin_amdgcn_mfma_f32_16x16x32_bf16(
              af[mt], bf[nt], acc[mt][nt], 0, 0, 0);
    }
    __builtin_amdgcn_sched_barrier(0);
    __builtin_amdgcn_s_barrier();  // reads of pa/pb done; next iter may write
  }

  // ---------------- Phase 2: epilogue scatter to LDS ----------------
  // C/D layout: col = c0 + ln, row t = wm + mt*16 + qd*4 + r.
#pragma unroll
  for (int nt = 0; nt < 6; ++nt) {
    const int c0 = wn + nt * 16;  // wave-uniform
#pragma unroll
    for (int mt = 0; mt < 4; ++mt) {
#pragma unroll
      for (int r = 0; r < 4; ++r) {
        const int t = wm + mt * 16 + qd * 4 + r;
        const u16 val = f2b(acc[mt][nt][r]);
        if (c0 < 64) {  // q -> linear [t][d]
          smem[QS_OFF + t * 64 + c0 + ln] = val;
        } else if (c0 < 128) {  // k -> fragment-major Kls
          const int d = c0 - 64 + ln;
          smem[KLS_OFF + ((t >> 4) << 10) + ((d >> 5) << 9) +
               (((d >> 3) & 3) << 7) + ((t & 15) << 3) + (d & 7)] = val;
        } else {  // v -> vTS [d][t], XOR-swizzled col
          const int dv = c0 - 128 + ln;
          smem[VTS_OFF + dv * 256 + (t ^ ((dv & 7) << 3))] = val;
        }
      }
    }
  }
  __syncthreads();

  // ---------------- Phase 3: causal flash attention ----------------
  u16* Pw = smem + PLS_OFF + w * 1152;
#pragma unroll
  for (int i = 0; i < 2; ++i) {
    const int mt = i ? (15 - w) : w;
    bf16x8 qf[2];
#pragma unroll
    for (int kc = 0; kc < 2; ++kc)
      qf[kc] = *(const bf16x8*)&smem[QS_OFF + (mt * 16 + ln) * 64 + kc * 32 +
                                     qd * 8];

    floatx4 oacc[4];
    float lsum[4];
#pragma unroll
    for (int dt = 0; dt < 4; ++dt) oacc[dt] = floatx4{0.f, 0.f, 0.f, 0.f};
#pragma unroll
    for (int r = 0; r < 4; ++r) lsum[r] = 0.f;

    const int cmax = mt >> 2;
    for (int c = 0; c < cmax; ++c)
      attn_chunk_f<false>(c, mt, lane, ln, qd, qf, smem, Pw, oacc, lsum);
    attn_chunk_f<true>(cmax, mt, lane, ln, qd, qf, smem, Pw, oacc, lsum);

#pragma unroll
    for (int off = 1; off < 16; off <<= 1)
#pragma unroll
      for (int r = 0; r < 4; ++r) lsum[r] += __shfl_xor(lsum[r], off);

    // y written with per-row col permutation for proj's swizzled read
#pragma unroll
    for (int r = 0; r < 4; ++r) {
      const float inv = 1.f / lsum[r];
      const int t = mt * 16 + qd * 4 + r;
      const int sy = (t & 7) << 3;
      u16* yo = y + ((size_t)b * T_DIM + t) * C_DIM + h * HS;
#pragma unroll
      for (int dt = 0; dt < 4; ++dt)
        yo[(dt * 16 + ln) ^ sy] = f2b(oacc[dt][r] * inv);
    }
  }
}

// ---------------------------------------------------------------------------
// Kernel C: output projection (round-3 verified, unchanged: DMA staging +
// XOR'd fragment reads; y and Wpt are K-pre-permuted).
// ---------------------------------------------------------------------------
__global__ __launch_bounds__(256) void proj_gemm(
    const u16* __restrict__ yb, const u16* __restrict__ Wpt,
    const float* __restrict__ bp, float* __restrict__ out) {
  __shared__ u16 As[128 * 64];
  __shared__ u16 Bs[128 * 64];
  const int row0 = blockIdx.x * 128;
  const int n0 = blockIdx.y * 128;
  const u16* a_rows = yb + (size_t)row0 * C_DIM;
  const u16* bt_rows = Wpt + (size_t)n0 * C_DIM;

  const int tid = threadIdx.x;
  const int lane = tid & 63;
  const int w = tid >> 6;
  const int lr = lane >> 3;
  const int lkc = (lane & 7) * 8;
  const int qd = lane >> 4;
  const int ln = lane & 15;
  const int sx = (ln & 7) << 3;
  const int mw = (w >> 1) * 64;
  const int nw = (w & 1) * 64;

  floatx4 acc[4][4];
#pragma unroll
  for (int i = 0; i < 4; ++i)
#pragma unroll
    for (int j = 0; j < 4; ++j) acc[i][j] = floatx4{0.f, 0.f, 0.f, 0.f};

  for (int kb = 0; kb < C_DIM / 64; ++kb) {
    const int k0 = kb * 64;
    __syncthreads();
#pragma unroll
    for (int s = 0; s < 4; ++s) {
      const int rbase = (s * 4 + w) * 8;
      gload_lds16(a_rows + (size_t)(rbase + lr) * C_DIM + k0 + lkc,
                  As + rbase * 64);
      gload_lds16(bt_rows + (size_t)(rbase + lr) * C_DIM + k0 + lkc,
                  Bs + rbase * 64);
    }
    __syncthreads();

#pragma unroll
    for (int kk = 0; kk < 2; ++kk) {
      bf16x8 af[4], bf[4];
#pragma unroll
      for (int mt = 0; mt < 4; ++mt)
        af[mt] = *(const bf16x8*)&As[(mw + mt * 16 + ln) * 64 +
                                     ((kk * 32 + qd * 8) ^ sx)];
#pragma unroll
      for (int nt = 0; nt < 4; ++nt)
        bf[nt] = *(const bf16x8*)&Bs[(nw + nt * 16 + ln) * 64 +
                                     ((kk * 32 + qd * 8) ^ sx)];
#pragma unroll
      for (int mt = 0; mt < 4; ++mt)
#pragma unroll
        for (int nt = 0; nt < 4; ++nt)
          acc[mt][nt] = __builtin_amdgcn_mfma_f32_16x16x32_bf16(
              af[mt], bf[nt], acc[mt][nt], 0, 0, 0);
    }
  }

#pragma unroll
  for (int nt = 0; nt < 4; ++nt) {
    const int col = n0 + nw + nt * 16 + ln;
    const float bias = bp[col];
#pragma unroll
    for (int mt = 0; mt < 4; ++mt) {
#pragma unroll
      for (int r = 0; r < 4; ++r) {
        const int grow = row0 + mw + mt * 16 + qd * 4 + r;
        out[(size_t)grow * C_DIM + col] = acc[mt][nt][r] + bias;
      }
    }
  }
}

// ---------------------------------------------------------------------------
extern "C" void kernel_launch(void* const* d_in, const int* in_sizes, int n_in,
                              void* d_out, int out_size, void* d_ws, size_t ws_size,
                              hipStream_t stream) {
  const float* x  = (const float*)d_in[0];
  const float* Wq = (const float*)d_in[1];
  const float* Wk = (const float*)d_in[2];
  const float* Wv = (const float*)d_in[3];
  const float* Wp = (const float*)d_in[4];
  const float* bp = (const float*)d_in[5];
  float* out = (float*)d_out;

  const size_t n_x = (size_t)NROWS * C_DIM;  // 12,582,912

  u16* Wh  = (u16*)d_ws;                       // [6][192][384] (K-permuted)
  u16* Wpt = Wh + (size_t)H_NUM * 192 * C_DIM; // [384][384]   (K-permuted)
  u16* xb  = Wpt + C_DIM * C_DIM;              // [32768][384] (K-permuted)
  u16* y   = xb + n_x;                         // [32768][384] (col-permuted)
  // ws: ~0.9 + 0.3 + 24 + 24 = ~49 MB

  prep_kernel<<<6144 + 2304, 256, 0, stream>>>(x, Wq, Wk, Wv, Wp, xb, Wh, Wpt);
  qkv_attn_fused<<<dim3(B_DIM, H_NUM), 512, 0, stream>>>(xb, Wh, y);
  proj_gemm<<<dim3(NROWS / 128, 3), 256, 0, stream>>>(y, Wpt, bp, out);
}